// Round 3
// baseline (1116.435 us; speedup 1.0000x reference)
//
#include <hip/hip_runtime.h>

// Flat dot-product reduction: out = (1/N) * sum_i probs[i]*centroids[i].
// Memory-bound: 808 MB read @ ~6.3 TB/s -> ~128 us floor.
// R2: removed contended fp64 atomic; block partials + finalize. (738.1 us)
// R4: 4x unroll, 8 loads in flight, NT loads. (737.0 us — dead flat vs R2)
// R5: MEASUREMENT PROBE. Profile shows timed region is dominated by harness
//     re-poison fills (1.6 GB writes @ 6.5 TB/s, ~250 us each); dot kernel
//     absent from top-5 => < 246 us, true time unknown (130? 240?).
//     Dispatch the identical dot kernel 4x: T_dot = (dur_us - 737.0)/3.
//     Correctness unchanged (replicas recompute the same partials).
//     NOTE: this round intentionally reports a worse dur_us; R4 is banked.

typedef float f32x4 __attribute__((ext_vector_type(4)));

#define NBLOCKS 2048
#define NTHREADS 256
#define PROBE_REPEATS 4

__global__ __launch_bounds__(NTHREADS) void dot_reduce_kernel(
    const f32x4* __restrict__ p4, const f32x4* __restrict__ c4,
    long n4, float* __restrict__ partials) {
    f32x4 acc0 = {0.f, 0.f, 0.f, 0.f};
    f32x4 acc1 = {0.f, 0.f, 0.f, 0.f};
    f32x4 acc2 = {0.f, 0.f, 0.f, 0.f};
    f32x4 acc3 = {0.f, 0.f, 0.f, 0.f};

    long tid    = (long)blockIdx.x * blockDim.x + threadIdx.x;
    long stride = (long)gridDim.x * blockDim.x;

    long i = tid;
    // Main 4x-unrolled loop: 8 independent 16B loads issued per trip.
    for (; i + 3 * stride < n4; i += 4 * stride) {
        f32x4 a0 = __builtin_nontemporal_load(p4 + i);
        f32x4 a1 = __builtin_nontemporal_load(p4 + i + stride);
        f32x4 a2 = __builtin_nontemporal_load(p4 + i + 2 * stride);
        f32x4 a3 = __builtin_nontemporal_load(p4 + i + 3 * stride);
        f32x4 b0 = __builtin_nontemporal_load(c4 + i);
        f32x4 b1 = __builtin_nontemporal_load(c4 + i + stride);
        f32x4 b2 = __builtin_nontemporal_load(c4 + i + 2 * stride);
        f32x4 b3 = __builtin_nontemporal_load(c4 + i + 3 * stride);
        acc0 += a0 * b0;
        acc1 += a1 * b1;
        acc2 += a2 * b2;
        acc3 += a3 * b3;
    }
    // Tail: at most 3 trips per thread.
    for (; i < n4; i += stride) {
        f32x4 a = __builtin_nontemporal_load(p4 + i);
        f32x4 b = __builtin_nontemporal_load(c4 + i);
        acc0 += a * b;
    }

    f32x4 acc = (acc0 + acc1) + (acc2 + acc3);
    float s = (acc.x + acc.y) + (acc.z + acc.w);

    // wave-64 shuffle reduction
    #pragma unroll
    for (int off = 32; off > 0; off >>= 1)
        s += __shfl_down(s, off, 64);

    __shared__ float wave_sums[NTHREADS / 64];
    int lane = threadIdx.x & 63;
    int wid  = threadIdx.x >> 6;
    if (lane == 0) wave_sums[wid] = s;
    __syncthreads();
    if (threadIdx.x == 0) {
        partials[blockIdx.x] = (wave_sums[0] + wave_sums[1]) +
                               (wave_sums[2] + wave_sums[3]);
    }
}

__global__ void finalize_kernel(const float* __restrict__ partials,
                                float* __restrict__ out, double inv_n) {
    // one block, 256 threads; each sums NBLOCKS/256 = 8 partials in double
    double s = 0.0;
    for (int i = threadIdx.x; i < NBLOCKS; i += NTHREADS)
        s += (double)partials[i];

    #pragma unroll
    for (int off = 32; off > 0; off >>= 1)
        s += __shfl_down(s, off, 64);

    __shared__ double wave_sums[NTHREADS / 64];
    int lane = threadIdx.x & 63;
    int wid  = threadIdx.x >> 6;
    if (lane == 0) wave_sums[wid] = s;
    __syncthreads();
    if (threadIdx.x == 0) {
        double tot = (wave_sums[0] + wave_sums[1]) +
                     (wave_sums[2] + wave_sums[3]);
        out[0] = (float)(tot * inv_n);
    }
}

extern "C" void kernel_launch(void* const* d_in, const int* in_sizes, int n_in,
                              void* d_out, int out_size, void* d_ws, size_t ws_size,
                              hipStream_t stream) {
    const float* probs     = (const float*)d_in[0];
    const float* centroids = (const float*)d_in[1];
    float* out = (float*)d_out;
    float* partials = (float*)d_ws;   // NBLOCKS floats of scratch

    long total = (long)in_sizes[0];   // N*K = 101,000,000 (divisible by 4)
    long n4    = total / 4;
    long rows  = total / 101;         // K = 101 per the reference

    // PROBE: repeat the identical dispatch to expose T_dot in dur_us.
    for (int r = 0; r < PROBE_REPEATS; ++r) {
        dot_reduce_kernel<<<dim3(NBLOCKS), dim3(NTHREADS), 0, stream>>>(
            (const f32x4*)probs, (const f32x4*)centroids, n4, partials);
    }

    finalize_kernel<<<1, NTHREADS, 0, stream>>>(partials, out, 1.0 / (double)rows);
}

// Round 4
// 733.797 us; speedup vs baseline: 1.5214x; 1.5214x over previous
//
#include <hip/hip_runtime.h>

// Flat dot-product reduction: out = (1/N) * sum_i probs[i]*centroids[i].
// Memory-bound: 808 MB read @ ~6.4 TB/s achievable -> ~126 us floor.
// R2: removed contended fp64 atomic; block partials + finalize. (738.1 us)
// R4: 4x unroll, 8 loads in flight, NT loads. (737.0 us — flat vs R2; MLP
//     was never the limit: 32 waves/CU x 2 loads ≈ 64 KB/CU in flight.)
// R5: 4x-dispatch probe => T_dot = (1116.4 - 737.0)/3 = 126.5 us
//     = 6.39 TB/s = 80% of peak, identical to the harness fills (80-82%)
//     and the measured device ceiling (~6.3-6.6 TB/s). KERNEL IS AT THE
//     HBM ROOFLINE. Remaining ~610 us of the timed region is harness
//     re-poison fillBufferAligned traffic (1.6 GB @ 82% peak), invariant
//     to kernel source.
// R6: restore the single-dispatch R4 kernel as the final artifact.

typedef float f32x4 __attribute__((ext_vector_type(4)));

#define NBLOCKS 2048
#define NTHREADS 256

__global__ __launch_bounds__(NTHREADS) void dot_reduce_kernel(
    const f32x4* __restrict__ p4, const f32x4* __restrict__ c4,
    long n4, float* __restrict__ partials) {
    f32x4 acc0 = {0.f, 0.f, 0.f, 0.f};
    f32x4 acc1 = {0.f, 0.f, 0.f, 0.f};
    f32x4 acc2 = {0.f, 0.f, 0.f, 0.f};
    f32x4 acc3 = {0.f, 0.f, 0.f, 0.f};

    long tid    = (long)blockIdx.x * blockDim.x + threadIdx.x;
    long stride = (long)gridDim.x * blockDim.x;

    long i = tid;
    // Main 4x-unrolled loop: 8 independent 16B loads issued per trip.
    for (; i + 3 * stride < n4; i += 4 * stride) {
        f32x4 a0 = __builtin_nontemporal_load(p4 + i);
        f32x4 a1 = __builtin_nontemporal_load(p4 + i + stride);
        f32x4 a2 = __builtin_nontemporal_load(p4 + i + 2 * stride);
        f32x4 a3 = __builtin_nontemporal_load(p4 + i + 3 * stride);
        f32x4 b0 = __builtin_nontemporal_load(c4 + i);
        f32x4 b1 = __builtin_nontemporal_load(c4 + i + stride);
        f32x4 b2 = __builtin_nontemporal_load(c4 + i + 2 * stride);
        f32x4 b3 = __builtin_nontemporal_load(c4 + i + 3 * stride);
        acc0 += a0 * b0;
        acc1 += a1 * b1;
        acc2 += a2 * b2;
        acc3 += a3 * b3;
    }
    // Tail: at most 3 trips per thread.
    for (; i < n4; i += stride) {
        f32x4 a = __builtin_nontemporal_load(p4 + i);
        f32x4 b = __builtin_nontemporal_load(c4 + i);
        acc0 += a * b;
    }

    f32x4 acc = (acc0 + acc1) + (acc2 + acc3);
    float s = (acc.x + acc.y) + (acc.z + acc.w);

    // wave-64 shuffle reduction
    #pragma unroll
    for (int off = 32; off > 0; off >>= 1)
        s += __shfl_down(s, off, 64);

    __shared__ float wave_sums[NTHREADS / 64];
    int lane = threadIdx.x & 63;
    int wid  = threadIdx.x >> 6;
    if (lane == 0) wave_sums[wid] = s;
    __syncthreads();
    if (threadIdx.x == 0) {
        partials[blockIdx.x] = (wave_sums[0] + wave_sums[1]) +
                               (wave_sums[2] + wave_sums[3]);
    }
}

__global__ void finalize_kernel(const float* __restrict__ partials,
                                float* __restrict__ out, double inv_n) {
    // one block, 256 threads; each sums NBLOCKS/256 = 8 partials in double
    double s = 0.0;
    for (int i = threadIdx.x; i < NBLOCKS; i += NTHREADS)
        s += (double)partials[i];

    #pragma unroll
    for (int off = 32; off > 0; off >>= 1)
        s += __shfl_down(s, off, 64);

    __shared__ double wave_sums[NTHREADS / 64];
    int lane = threadIdx.x & 63;
    int wid  = threadIdx.x >> 6;
    if (lane == 0) wave_sums[wid] = s;
    __syncthreads();
    if (threadIdx.x == 0) {
        double tot = (wave_sums[0] + wave_sums[1]) +
                     (wave_sums[2] + wave_sums[3]);
        out[0] = (float)(tot * inv_n);
    }
}

extern "C" void kernel_launch(void* const* d_in, const int* in_sizes, int n_in,
                              void* d_out, int out_size, void* d_ws, size_t ws_size,
                              hipStream_t stream) {
    const float* probs     = (const float*)d_in[0];
    const float* centroids = (const float*)d_in[1];
    float* out = (float*)d_out;
    float* partials = (float*)d_ws;   // NBLOCKS floats of scratch

    long total = (long)in_sizes[0];   // N*K = 101,000,000 (divisible by 4)
    long n4    = total / 4;
    long rows  = total / 101;         // K = 101 per the reference

    dot_reduce_kernel<<<dim3(NBLOCKS), dim3(NTHREADS), 0, stream>>>(
        (const f32x4*)probs, (const f32x4*)centroids, n4, partials);

    finalize_kernel<<<1, NTHREADS, 0, stream>>>(partials, out, 1.0 / (double)rows);
}